// Round 3
// baseline (822.316 us; speedup 1.0000x reference)
//
#include <hip/hip_runtime.h>
#include <stdint.h>
#include <stddef.h>

// sources (B,T,N,D) fp32, queries (L,D) fp32, layer_idx int scalar.
// out (B,T,D) fp32.  B*T = 32768, N = 9, D = 512.
static constexpr int D = 512;
static constexpr int N = 9;
static constexpr float EPS = 1e-6f;

// v4: occupancy fix. The register-resident one-wave-per-bt structure held
// ~130 VGPRs -> 2 waves/SIMD (halving at >128, m69) -> kernel ran at
// 1.7 TB/s (27% of achievable). Now ONE BLOCK (4 waves) per (b,t):
// thread i owns float2 #i of each of the 9 rows -> payload 18 VGPRs,
// peak live ~50 -> __launch_bounds__(256,8) caps at 64 VGPR, 8 waves/SIMD.
// Sources stay register-resident (single HBM read, round-1 lesson), the
// rms/dot reduction is 6-step interleaved butterfly + 288 B LDS cross-wave
// combine (broadcast reads, conflict-free).
__global__ __launch_bounds__(256, 8) void block_attn(
    const float2* __restrict__ src2,
    const float2* __restrict__ q2,
    const int*   __restrict__ layer_idx,
    float2* __restrict__ out2,
    int bt_total)
{
    const int tid  = threadIdx.x;
    const int lane = tid & 63;
    const int wave = tid >> 6;
    const int bt   = blockIdx.x;
    if (bt >= bt_total) return;

    // [n][wave] for ss (n<9) and dt (n-9 for n>=9); rows 16 B so float4-readable
    __shared__ __align__(16) float red[2 * N][4];

    const int li = layer_idx[0];
    const float2 w = q2[(size_t)li * (D / 2) + tid];

    // thread i reads float2 #i of each row: wave-wide dwordx2, 512 B/instr,
    // block covers the full 18 KiB (b,t) tile contiguously.
    const float2* p = src2 + (size_t)bt * (size_t)(N * (D / 2)) + tid;

    float2 s[N];                 // register-resident slice (single HBM read)
    float  ss[N], dt[N];         // per-thread partials
#pragma unroll
    for (int n = 0; n < N; ++n) {
        const float2 v = p[n * (D / 2)];
        s[n] = v;
        ss[n] = fmaf(v.x, v.x, v.y * v.y);
        dt[n] = fmaf(v.x, w.x, v.y * w.y);
    }

    // 18 independent butterfly chains, interleaved per step (round-2 win)
#pragma unroll
    for (int m = 1; m < 64; m <<= 1) {
#pragma unroll
        for (int n = 0; n < N; ++n) {
            ss[n] += __shfl_xor(ss[n], m, 64);
            dt[n] += __shfl_xor(dt[n], m, 64);
        }
    }

    // cross-wave combine: 18 lanes/wave write one float each, then all
    // threads read the per-wave totals back (same-address broadcast).
    if (lane < 2 * N) {
        red[lane][wave] = (lane < N) ? ss[lane] : dt[lane - N];
    }
    __syncthreads();

    float score[N];
#pragma unroll
    for (int n = 0; n < N; ++n) {
        const float4 a = *(const float4*)red[n];       // ss per wave
        const float4 b = *(const float4*)red[n + N];   // dt per wave
        const float S = (a.x + a.y) + (a.z + a.w);
        const float T = (b.x + b.y) + (b.z + b.w);
        // score = dot(s,w)/rms, rms = sqrt(mean(s^2)+eps)
        score[n] = T * rsqrtf(S * (1.0f / 512.0f) + EPS);
    }

    // softmax over N=9 (every thread holds all scores)
    float mx = score[0];
#pragma unroll
    for (int n = 1; n < N; ++n) mx = fmaxf(mx, score[n]);
    float asum = 0.f;
    float alpha[N];
#pragma unroll
    for (int n = 0; n < N; ++n) { alpha[n] = __expf(score[n] - mx); asum += alpha[n]; }
    const float inv = 1.0f / asum;

    // h = sum_n alpha_n * sources_n  (from registers)
    float2 h = {0.f, 0.f};
#pragma unroll
    for (int n = 0; n < N; ++n) {
        const float an = alpha[n] * inv;
        h.x = fmaf(an, s[n].x, h.x);
        h.y = fmaf(an, s[n].y, h.y);
    }

    out2[(size_t)bt * (D / 2) + tid] = h;
}

extern "C" void kernel_launch(void* const* d_in, const int* in_sizes, int n_in,
                              void* d_out, int out_size, void* d_ws, size_t ws_size,
                              hipStream_t stream) {
    (void)n_in; (void)d_ws; (void)ws_size;
    const float2* src = (const float2*)d_in[0];
    const float2* q   = (const float2*)d_in[1];
    const int*    li  = (const int*)d_in[2];
    float2* out = (float2*)d_out;

    // Unit disambiguation (harmless either way): layer_idx is a single
    // scalar, so its in_sizes entry is 1 if element units, 4/8 if bytes.
    const bool elem_units = (in_sizes[2] == 1);
    const long long src_elems = elem_units ? (long long)in_sizes[0]
                                           : (long long)in_sizes[0] / 4;
    const long long bt_total = src_elems / (long long)(N * D);   // = 32768

    block_attn<<<(int)bt_total, 256, 0, stream>>>(src, q, li, out, (int)bt_total);
}